// Round 7
// baseline (615.079 us; speedup 1.0000x reference)
//
#include <hip/hip_runtime.h>
#include <math.h>

#define NATOMS 20000
#define NEDGES 400000
#define EMBD   256
#define NRBF   50
#define NGATE  10
#define FOUT   128
#define APB    8       // atoms per block in k_main
#define OUTERC 5.0f

#define RBF_D    (5.0f/49.0f)
#define RBF_INVD (49.0f/5.0f)
#define RBF_C2   (-0.5f*(49.0f/5.0f)*(49.0f/5.0f)*1.4426950408889634f)
#define PI_OVER_OUTER 0.62831853071795864769f

static __device__ __forceinline__ float softplusf(float x){
    return (x > 15.0f) ? x : log1pf(__expf(x));
}
// round-to-nearest-even bf16, result in HIGH 16 bits
static __device__ __forceinline__ unsigned bfr(float v){
    unsigned u = __float_as_uint(v);
    return (u + 0x7fffu + ((u >> 16) & 1u)) & 0xffff0000u;
}
#define BLO(u) __uint_as_float((u) << 16)
#define BHI(u) __uint_as_float((u) & 0xffff0000u)

// ================= k_a: gate/R/sv rows (blocks 0..51) + degree count (52..) ======
__global__ __launch_bounds__(256) void k_a(
    const float* __restrict__ Wd, const float* __restrict__ Wdt,
    const float* __restrict__ bd, const float* __restrict__ bdt,
    const float* __restrict__ bgam, const float* __restrict__ Wgam,
    const float* __restrict__ Wexp, const float* __restrict__ bexp,
    const float* __restrict__ Wg, const float* __restrict__ Wn,
    const int* __restrict__ esrc, int* __restrict__ counts,
    float* __restrict__ R0, float* __restrict__ R1,
    float* __restrict__ Qg, float* __restrict__ Qn, float* __restrict__ sv)
{
    const int b = blockIdx.x, t = threadIdx.x;
    if (b >= 52) {
        int e = (b - 52) * 256 + t;
        if (e < NEDGES) atomicAdd(&counts[esrc[e]], 1);
        return;
    }
    __shared__ float ya[256], za[256];
    const int m = b;    // 0..51 rows of Y=[Wd@Wdt(50); bd@Wdt; bdt]
    float s;
    if (m < 50) {
        const float* wr = Wd + m*EMBD;
        s = 0.f;
        #pragma unroll 8
        for (int k = 0; k < EMBD; k++) s += wr[k] * Wdt[k*EMBD + t];
    } else if (m == 50) {
        s = 0.f;
        #pragma unroll 8
        for (int k = 0; k < EMBD; k++) s += bd[k] * Wdt[k*EMBD + t];
    } else {
        s = bdt[t];
    }
    ya[t] = s;
    __syncthreads();
    s = 0.f;
    #pragma unroll 8
    for (int k = 0; k < EMBD; k++) s += ya[k] * Wgam[k*EMBD + t];
    if (m == 51) s += bgam[t];
    za[t] = s;
    __syncthreads();
    const int half = t >> 7, ff = t & 127;
    const float* WX = Wexp + (size_t)half*EMBD*FOUT;
    s = 0.f;
    #pragma unroll 8
    for (int k = 0; k < EMBD; k++) s += za[k] * WX[k*FOUT + ff];
    if (m < 50)       (half ? R1 : R0)[m*FOUT + ff] = s;
    else if (m == 50) sv[half*FOUT + ff] = s;
    else              sv[256 + half*FOUT + ff] = s + bexp[half*FOUT + ff];
    if (t < 20) {
        const int tt = t % 10;
        const float* WT = (t < 10) ? Wg : Wn;
        float q = 0.f;
        #pragma unroll 8
        for (int k = 0; k < EMBD; k++) q += ya[k] * WT[k*NGATE + tt];
        if (m < 50) { float* Q = (t < 10) ? Qg : Qn; Q[m*12 + tt] = q; }
        else {
            int off = (m == 50) ? ((t < 10) ? 512 : 532) : ((t < 10) ? 522 : 542);
            sv[off + tt] = q;
            float* Q = (t < 10) ? Qg : Qn; Q[m*12 + tt] = 0.f;   // zero-pad rows 50,51
        }
    }
}

// ================= k_b: edge transform, COALESCED writes in edge order ==========
// rrS[e] = 8 dwords: 6 words of bf16 rr[0..11] + ab(Cg0,Cg1) + gg(g0,g1)
// rec2[e] = 2 dwords: xy(ex,ey), ezd(ez | j0<<8 | zd)
__global__ __launch_bounds__(256) void k_b(
    const int* __restrict__ z, const int* __restrict__ esrc, const int* __restrict__ edst,
    const float* __restrict__ ew, const float* __restrict__ evec, const float* __restrict__ noise,
    const float* __restrict__ Qg, const float* __restrict__ Qn, const float* __restrict__ sv,
    uint4* __restrict__ rrS, uint2* __restrict__ rec2)
{
    __shared__ float qgL[52*12], qnL[52*12];
    __shared__ float nbuf[256*11];
    __shared__ float vbuf[768];
    const int t = threadIdx.x;
    const int e0 = blockIdx.x * 256;

    for (int i = t; i < 52*12; i += 256) { qgL[i] = Qg[i]; qnL[i] = Qn[i]; }
    #pragma unroll
    for (int q = 0; q < 10; q++) {
        int idx = q*256 + t; long long g = (long long)e0*10 + idx;
        if (g < (long long)NEDGES*10) { int r_ = idx/10; nbuf[r_*11 + (idx - r_*10)] = noise[g]; }
    }
    #pragma unroll
    for (int q = 0; q < 3; q++) {
        int idx = q*256 + t; long long g = (long long)e0*3 + idx;
        if (g < (long long)NEDGES*3) vbuf[idx] = evec[g];
    }
    __syncthreads();

    int e = e0 + t;
    if (e >= NEDGES) return;
    float w = ew[e];
    float C = (w < OUTERC) ? 0.5f*(__cosf(w*PI_OVER_OUTER) + 1.0f) : 0.0f;
    int iw = (int)(w * RBF_INVD);
    int j0 = (iw - 4) & ~3;
    j0 = max(0, min(40, j0));
    float rW[12];
    #pragma unroll
    for (int k = 0; k < 12; k++) { float tt = w - (j0+k)*RBF_D; rW[k] = exp2f(RBF_C2*tt*tt); }
    float hg[NGATE], hn[NGATE];
    #pragma unroll
    for (int g2 = 0; g2 < NGATE; g2++) { hg[g2] = 0.f; hn[g2] = 0.f; }
    #pragma unroll
    for (int k = 0; k < 12; k++) {
        float rk = rW[k];
        const float* qg = &qgL[(j0+k)*12];
        const float* qn = &qnL[(j0+k)*12];
        float4 ga = *(const float4*)qg; float4 gb = *(const float4*)(qg+4);
        float2 gc = *(const float2*)(qg+8);
        float4 na = *(const float4*)qn; float4 nb = *(const float4*)(qn+4);
        float2 nc = *(const float2*)(qn+8);
        hg[0]=fmaf(rk,ga.x,hg[0]); hg[1]=fmaf(rk,ga.y,hg[1]); hg[2]=fmaf(rk,ga.z,hg[2]); hg[3]=fmaf(rk,ga.w,hg[3]);
        hg[4]=fmaf(rk,gb.x,hg[4]); hg[5]=fmaf(rk,gb.y,hg[5]); hg[6]=fmaf(rk,gb.z,hg[6]); hg[7]=fmaf(rk,gb.w,hg[7]);
        hg[8]=fmaf(rk,gc.x,hg[8]); hg[9]=fmaf(rk,gc.y,hg[9]);
        hn[0]=fmaf(rk,na.x,hn[0]); hn[1]=fmaf(rk,na.y,hn[1]); hn[2]=fmaf(rk,na.z,hn[2]); hn[3]=fmaf(rk,na.w,hn[3]);
        hn[4]=fmaf(rk,nb.x,hn[4]); hn[5]=fmaf(rk,nb.y,hn[5]); hn[6]=fmaf(rk,nb.z,hn[6]); hn[7]=fmaf(rk,nb.w,hn[7]);
        hn[8]=fmaf(rk,nc.x,hn[8]); hn[9]=fmaf(rk,nc.y,hn[9]);
    }
    float H[NGATE];
    #pragma unroll
    for (int g2 = 0; g2 < NGATE; g2++) {
        float gv = C*(hg[g2] + sv[512+g2]) + sv[522+g2];
        float nv = C*(hn[g2] + sv[532+g2]) + sv[542+g2];
        H[g2] = gv + nbuf[t*11 + g2] * softplusf(nv);
    }
    float m1 = -INFINITY, m2 = -INFINITY;
    #pragma unroll
    for (int g2 = 0; g2 < NGATE; g2++) {
        float v = H[g2];
        if (v > m1) { m2 = m1; m1 = v; } else if (v > m2) { m2 = v; }
    }
    float den = 0.f;
    #pragma unroll
    for (int g2 = 0; g2 < NGATE; g2++) den += (H[g2] >= m2) ? __expf(H[g2] - m1) : 0.f;
    float inv = 1.0f / den;
    float g0 = inv;
    float g1 = __expf(m2 - m1) * inv;

    float ex = vbuf[t*3+0], ey = vbuf[t*3+1], ez = vbuf[t*3+2];
    float rn = rsqrtf(ex*ex + ey*ey + ez*ez);
    ex *= rn; ey *= rn; ez *= rn;
    int zd = z[edst[e]];

    uint4 A = make_uint4((bfr(rW[0])>>16)|bfr(rW[1]),  (bfr(rW[2])>>16)|bfr(rW[3]),
                         (bfr(rW[4])>>16)|bfr(rW[5]),  (bfr(rW[6])>>16)|bfr(rW[7]));
    uint4 B = make_uint4((bfr(rW[8])>>16)|bfr(rW[9]),  (bfr(rW[10])>>16)|bfr(rW[11]),
                         (bfr(C*g0)>>16)|bfr(C*g1),    (bfr(g0)>>16)|bfr(g1));
    rrS[(size_t)e*2]   = A;
    rrS[(size_t)e*2+1] = B;
    rec2[e] = make_uint2((bfr(ex)>>16)|bfr(ey), bfr(ez) | ((unsigned)j0<<8) | (unsigned)zd);
}

// ================= k_c: exclusive scan (block 0) + Ti/Tj tables (blocks 1..200) ==
__global__ __launch_bounds__(256) void k_c(
    const int* __restrict__ counts, int* __restrict__ cursors,
    const float* __restrict__ emb,
    const float* __restrict__ Wai, const float* __restrict__ bai,
    const float* __restrict__ Waj, const float* __restrict__ baj,
    const float* __restrict__ Wgam, const float* __restrict__ Wexp,
    float* __restrict__ Ti0, float* __restrict__ Ti1,
    float* __restrict__ Tj0, float* __restrict__ Tj1)
{
    const int b = blockIdx.x, t = threadIdx.x;
    if (b == 0) {
        __shared__ int part[256];
        const int CH = (NATOMS + 255) / 256;
        int base = t * CH, s = 0;
        for (int i = 0; i < CH; i++) { int idx = base + i; if (idx < NATOMS) s += counts[idx]; }
        part[t] = s;
        __syncthreads();
        for (int d = 1; d < 256; d <<= 1) {
            int v = (t >= d) ? part[t - d] : 0;
            __syncthreads();
            part[t] += v;
            __syncthreads();
        }
        int run = (t == 0) ? 0 : part[t - 1];
        for (int i = 0; i < CH; i++) {
            int idx = base + i;
            if (idx < NATOMS) { cursors[idx] = run; run += counts[idx]; }
        }
        return;
    }
    __shared__ float ya[256], za[256];
    const int side = (b >= 101);
    const int m = side ? b - 101 : b - 1;
    const float* er = emb + m*EMBD;
    const float* W1 = side ? Waj : Wai;
    const float* b1 = side ? baj : bai;
    float s = b1[t];
    #pragma unroll 8
    for (int k = 0; k < EMBD; k++) s += er[k] * W1[k*EMBD + t];
    ya[t] = s;
    __syncthreads();
    const float* G = Wgam + (size_t)(side ? 512 : 256) * EMBD;
    s = 0.f;
    #pragma unroll 8
    for (int k = 0; k < EMBD; k++) s += ya[k] * G[k*EMBD + t];
    za[t] = s;
    __syncthreads();
    const int half = t >> 7, ff = t & 127;
    const float* WX = Wexp + (size_t)half*EMBD*FOUT;
    s = 0.f;
    #pragma unroll 8
    for (int k = 0; k < EMBD; k++) s += za[k] * WX[k*FOUT + ff];
    float* dst = side ? (half ? Tj1 : Tj0) : (half ? Ti1 : Ti0);
    dst[m*FOUT + ff] = s;
}

// ================= k_d: perm scatter (one 4B word per edge) =====================
// perm word = e | zd<<19 | (j0/4)<<26
__global__ __launch_bounds__(256) void k_d(
    const int* __restrict__ esrc, const uint2* __restrict__ rec2,
    int* __restrict__ cursors, unsigned* __restrict__ perm)
{
    int e = blockIdx.x * 256 + threadIdx.x;
    if (e >= NEDGES) return;
    unsigned ezd = rec2[e].y;
    int p = atomicAdd(&cursors[esrc[e]], 1);
    perm[p] = (unsigned)e | ((ezd & 0x7fu) << 19) | (((ezd >> 10) & 0xfu) << 26);
    if (e < 16) perm[NEDGES + e] = 0;   // safety pad for prefetch over-read
}

// ================= k_main: scalar-record pipeline, no LDS staging ===============
#define DOTX(J) { acc =      BLO(Aw.x)*Rc[J]; \
  acc = fmaf(BHI(Aw.x), Rc[(J)+1],  acc); acc = fmaf(BLO(Aw.y), Rc[(J)+2],  acc); \
  acc = fmaf(BHI(Aw.y), Rc[(J)+3],  acc); acc = fmaf(BLO(Aw.z), Rc[(J)+4],  acc); \
  acc = fmaf(BHI(Aw.z), Rc[(J)+5],  acc); acc = fmaf(BLO(Aw.w), Rc[(J)+6],  acc); \
  acc = fmaf(BHI(Aw.w), Rc[(J)+7],  acc); acc = fmaf(BLO(Bw.x), Rc[(J)+8],  acc); \
  acc = fmaf(BHI(Bw.x), Rc[(J)+9],  acc); acc = fmaf(BLO(Bw.y), Rc[(J)+10], acc); \
  acc = fmaf(BHI(Bw.y), Rc[(J)+11], acc); }

#define FLUSH() { \
    accS[aCur-aBeg][pair][f] = make_float4(accA,accX,accY,accZ); \
    accA=accX=accY=accZ=0.f; aCur++; \
    if (aCur < aEnd) { nextEnd = neNxt; dtV = dV + tiNxt; \
        int an = aCur + 1; \
        if (an < aEnd) { neNxt = cursors[an]; tiNxt = TiT[z[an]*FOUT + f]; } \
    } else nextEnd = 0x7fffffff; }

#define COMP(K) { \
    int gi = eBeg + i + (K); \
    while (gi == nextEnd) FLUSH() \
    uint4 Aw = edA[K], Bw = edB4[K]; uint2 Cw = edc[K]; \
    float aa  = pair ? BHI(Bw.z) : BLO(Bw.z); \
    float gg_ = pair ? BHI(Bw.w) : BLO(Bw.w); \
    float acc; \
    switch ((pmC[K] >> 26) & 0xf) { \
      case 0: DOTX(0)  break; case 1: DOTX(4)  break; case 2: DOTX(8)  break; \
      case 3: DOTX(12) break; case 4: DOTX(16) break; case 5: DOTX(20) break; \
      case 6: DOTX(24) break; case 7: DOTX(28) break; case 8: DOTX(32) break; \
      case 9: DOTX(36) break; default: DOTX(40) break; } \
    float part_ = fmaf(aa, acc + sV, gg_ * (dtV + tjC[K])); \
    accA += part_; \
    accX = fmaf(BLO(Cw.x), part_, accX); \
    accY = fmaf(BHI(Cw.x), part_, accY); \
    accZ = fmaf(BHI(Cw.y), part_, accZ); }

__global__ __launch_bounds__(256, 3) void k_main(
    const int* __restrict__ z, const int* __restrict__ cursors,
    const unsigned* __restrict__ perm,
    const uint4* __restrict__ rrS, const uint2* __restrict__ rec2,
    const float* __restrict__ R0, const float* __restrict__ R1,
    const float* __restrict__ Ti0, const float* __restrict__ Ti1,
    const float* __restrict__ Tj0, const float* __restrict__ Tj1,
    const float* __restrict__ sv, float* __restrict__ out)
{
    __shared__ float4 accS[APB][2][FOUT];
    const int tid = threadIdx.x, pair = tid >> 7, f = tid & 127;

    float Rc[52];
    const float* Rtab = pair ? R1 : R0;
    #pragma unroll
    for (int j = 0; j < NRBF; j++) Rc[j] = Rtab[j*FOUT + f];
    Rc[50] = 0.f; Rc[51] = 0.f;
    const float* TiT = pair ? Ti1 : Ti0;
    const float* TjT = pair ? Tj1 : Tj0;
    const float sV = sv[pair*FOUT + f];
    const float dV = sv[256 + pair*FOUT + f];

    const int aBeg = blockIdx.x * APB, aEnd = aBeg + APB;
    const int eBeg = aBeg ? cursors[aBeg-1] : 0;
    const int eEnd = cursors[aEnd-1];

    int aCur = aBeg;
    int nextEnd = cursors[aCur];
    float dtV = dV + TiT[z[aCur]*FOUT + f];
    int   neNxt = (aBeg+1 < aEnd) ? cursors[aBeg+1] : 0x7fffffff;
    float tiNxt = (aBeg+1 < aEnd) ? TiT[z[aBeg+1]*FOUT + f] : 0.f;
    float accA=0.f, accX=0.f, accY=0.f, accZ=0.f;

    const int n4 = ((eEnd - eBeg) + 3) & ~3;
    unsigned pmC[4], pmB[4];
    uint4 edA[4], edB4[4]; uint2 edc[4];
    float tjC[4];
    #pragma unroll
    for (int k = 0; k < 4; k++) pmC[k] = (unsigned)__builtin_amdgcn_readfirstlane((int)perm[eBeg+k]);
    #pragma unroll
    for (int k = 0; k < 4; k++) pmB[k] = (unsigned)__builtin_amdgcn_readfirstlane((int)perm[eBeg+4+k]);
    #pragma unroll
    for (int k = 0; k < 4; k++) { unsigned pe = pmC[k] & 0x7ffff;
        edA[k] = rrS[(size_t)pe*2]; edB4[k] = rrS[(size_t)pe*2+1]; edc[k] = rec2[pe]; }
    #pragma unroll
    for (int k = 0; k < 4; k++) tjC[k] = TjT[((pmC[k]>>19)&0x7f)*FOUT + f];

    for (int i = 0; i < n4; i += 4) {
        uint4 nA[4], nB[4]; uint2 nc[4]; float tjN[4]; unsigned pmN[4];
        #pragma unroll
        for (int k = 0; k < 4; k++) { unsigned pe = pmB[k] & 0x7ffff;
            nA[k] = rrS[(size_t)pe*2]; nB[k] = rrS[(size_t)pe*2+1]; nc[k] = rec2[pe]; }
        #pragma unroll
        for (int k = 0; k < 4; k++) tjN[k] = TjT[((pmB[k]>>19)&0x7f)*FOUT + f];
        #pragma unroll
        for (int k = 0; k < 4; k++) pmN[k] = (unsigned)__builtin_amdgcn_readfirstlane((int)perm[eBeg+i+8+k]);

        COMP(0) COMP(1) COMP(2) COMP(3)

        #pragma unroll
        for (int k = 0; k < 4; k++) {
            pmC[k] = pmB[k]; pmB[k] = pmN[k];
            edA[k] = nA[k]; edB4[k] = nB[k]; edc[k] = nc[k]; tjC[k] = tjN[k];
        }
    }
    while (aCur < aEnd) {
        accS[aCur-aBeg][pair][f] = make_float4(accA, accX, accY, accZ);
        accA=accX=accY=accZ=0.f; aCur++;
    }
    __syncthreads();
    if (tid < FOUT) {
        #pragma unroll
        for (int a2 = 0; a2 < APB; a2++) {
            float4 v0 = accS[a2][0][tid];
            float4 v1 = accS[a2][1][tid];
            int atom = aBeg + a2;
            out[(size_t)atom*FOUT + tid] = v0.x + v1.x;
            float* vb = out + (size_t)NATOMS*FOUT + (size_t)atom*3*FOUT;
            vb[tid]        = v0.y + v1.y;
            vb[FOUT+tid]   = v0.z + v1.z;
            vb[2*FOUT+tid] = v0.w + v1.w;
        }
    }
}

extern "C" void kernel_launch(void* const* d_in, const int* in_sizes, int n_in,
                              void* d_out, int out_size, void* d_ws, size_t ws_size,
                              hipStream_t stream)
{
    const int*   z    = (const int*)d_in[0];
    const int*   ei   = (const int*)d_in[3];
    const int*   esrc = ei;
    const int*   edst = ei + NEDGES;
    const float* ew   = (const float*)d_in[4];
    const float* evec = (const float*)d_in[5];
    const float* nz   = (const float*)d_in[6];
    const float* emb  = (const float*)d_in[7];
    const float* Wd   = (const float*)d_in[8];
    const float* bd   = (const float*)d_in[9];
    const float* Wdt  = (const float*)d_in[10];
    const float* bdt  = (const float*)d_in[11];
    const float* Wai  = (const float*)d_in[12];
    const float* bai  = (const float*)d_in[13];
    const float* Waj  = (const float*)d_in[14];
    const float* baj  = (const float*)d_in[15];
    const float* Wgam = (const float*)d_in[16];
    const float* bgam = (const float*)d_in[17];
    const float* Wg   = (const float*)d_in[18];
    const float* Wn   = (const float*)d_in[19];
    const float* Wexp = (const float*)d_in[20];
    const float* bexp = (const float*)d_in[21];
    float* out = (float*)d_out;

    char* w = (char*)d_ws;
    auto alloc = [&](size_t bytes) -> void* {
        void* p = (void*)w;
        w += (bytes + 255) & ~(size_t)255;
        return p;
    };
    int*   counts  = (int*)alloc(NATOMS * 4);
    int*   cursors = (int*)alloc(NATOMS * 4);
    float* R0  = (float*)alloc(NRBF*FOUT*4);
    float* R1  = (float*)alloc(NRBF*FOUT*4);
    float* Qg  = (float*)alloc(52*12*4);
    float* Qn  = (float*)alloc(52*12*4);
    float* Ti0 = (float*)alloc(100*FOUT*4);
    float* Ti1 = (float*)alloc(100*FOUT*4);
    float* Tj0 = (float*)alloc(100*FOUT*4);
    float* Tj1 = (float*)alloc(100*FOUT*4);
    float* sv  = (float*)alloc(552*4);
    uint4*    rrS  = (uint4*)alloc((size_t)NEDGES*32);
    uint2*    rec2 = (uint2*)alloc((size_t)NEDGES*8);
    unsigned* perm = (unsigned*)alloc(((size_t)NEDGES + 16)*4);

    hipMemsetAsync(counts, 0, NATOMS*4, stream);

    {
        int grid = 52 + (NEDGES + 255) / 256;   // 1615
        k_a<<<grid, 256, 0, stream>>>(Wd, Wdt, bd, bdt, bgam, Wgam, Wexp, bexp,
                                      Wg, Wn, esrc, counts, R0, R1, Qg, Qn, sv);
    }
    {
        int grid = (NEDGES + 255) / 256;        // 1563
        k_b<<<grid, 256, 0, stream>>>(z, esrc, edst, ew, evec, nz,
                                      Qg, Qn, sv, rrS, rec2);
    }
    k_c<<<201, 256, 0, stream>>>(counts, cursors, emb, Wai, bai, Waj, baj,
                                 Wgam, Wexp, Ti0, Ti1, Tj0, Tj1);
    {
        int grid = (NEDGES + 255) / 256;        // 1563
        k_d<<<grid, 256, 0, stream>>>(esrc, rec2, cursors, perm);
    }
    {
        int grid = NATOMS / APB;                // 2500
        k_main<<<grid, 256, 0, stream>>>(z, cursors, perm, rrS, rec2,
                                         R0, R1, Ti0, Ti1, Tj0, Tj1, sv, out);
    }
}

// Round 8
// 446.266 us; speedup vs baseline: 1.3783x; 1.3783x over previous
//
#include <hip/hip_runtime.h>
#include <math.h>

#define NATOMS 20000
#define NEDGES 400000
#define EMBD   256
#define NRBF   50
#define NGATE  10
#define FOUT   128
#define APB    8       // atoms per block in k_main
#define OUTERC 5.0f

#define RBF_D    (5.0f/49.0f)
#define RBF_INVD (49.0f/5.0f)
#define RBF_C2   (-0.5f*(49.0f/5.0f)*(49.0f/5.0f)*1.4426950408889634f)
#define PI_OVER_OUTER 0.62831853071795864769f

static __device__ __forceinline__ float softplusf(float x){
    return (x > 15.0f) ? x : __logf(1.0f + __expf(x));
}
// round-to-nearest-even bf16, result in HIGH 16 bits
static __device__ __forceinline__ unsigned bfr(float v){
    unsigned u = __float_as_uint(v);
    return (u + 0x7fffu + ((u >> 16) & 1u)) & 0xffff0000u;
}
#define BLO(u) __uint_as_float((u) << 16)
#define BHI(u) __uint_as_float((u) & 0xffff0000u)

// ================= k_ag: gate/R/sv rows (blocks 0..51) + degree count (52..) ======
__global__ __launch_bounds__(256) void k_ag(
    const float* __restrict__ Wd, const float* __restrict__ Wdt,
    const float* __restrict__ bd, const float* __restrict__ bdt,
    const float* __restrict__ bgam, const float* __restrict__ Wgam,
    const float* __restrict__ Wexp, const float* __restrict__ bexp,
    const float* __restrict__ Wg, const float* __restrict__ Wn,
    const int* __restrict__ esrc, int* __restrict__ counts,
    float* __restrict__ R0, float* __restrict__ R1,
    float* __restrict__ Qg, float* __restrict__ Qn, float* __restrict__ sv)
{
    const int b = blockIdx.x, t = threadIdx.x;
    if (b >= 52) {
        int e = (b - 52) * 256 + t;
        if (e < NEDGES) atomicAdd(&counts[esrc[e]], 1);
        return;
    }
    __shared__ float ya[256], za[256];
    const int m = b;    // 0..51 rows of Y=[Wd@Wdt(50); bd@Wdt; bdt]
    float s;
    if (m < 50) {
        const float* wr = Wd + m*EMBD;
        s = 0.f;
        #pragma unroll 8
        for (int k = 0; k < EMBD; k++) s += wr[k] * Wdt[k*EMBD + t];
    } else if (m == 50) {
        s = 0.f;
        #pragma unroll 8
        for (int k = 0; k < EMBD; k++) s += bd[k] * Wdt[k*EMBD + t];
    } else {
        s = bdt[t];
    }
    ya[t] = s;
    __syncthreads();
    s = 0.f;
    #pragma unroll 8
    for (int k = 0; k < EMBD; k++) s += ya[k] * Wgam[k*EMBD + t];
    if (m == 51) s += bgam[t];
    za[t] = s;
    __syncthreads();
    const int half = t >> 7, ff = t & 127;
    const float* WX = Wexp + (size_t)half*EMBD*FOUT;
    s = 0.f;
    #pragma unroll 8
    for (int k = 0; k < EMBD; k++) s += za[k] * WX[k*FOUT + ff];
    if (m < 50)       (half ? R1 : R0)[m*FOUT + ff] = s;
    else if (m == 50) sv[half*FOUT + ff] = s;
    else              sv[256 + half*FOUT + ff] = s + bexp[half*FOUT + ff];
    if (t < 20) {
        const int tt = t % 10;
        const float* WT = (t < 10) ? Wg : Wn;
        float q = 0.f;
        #pragma unroll 8
        for (int k = 0; k < EMBD; k++) q += ya[k] * WT[k*NGATE + tt];
        if (m < 50) { float* Q = (t < 10) ? Qg : Qn; Q[m*12 + tt] = q; }
        else {
            int off = (m == 50) ? ((t < 10) ? 512 : 532) : ((t < 10) ? 522 : 542);
            sv[off + tt] = q;
            float* Q = (t < 10) ? Qg : Qn; Q[m*12 + tt] = 0.f;   // zero-pad rows 50,51
        }
    }
}

// ================= k_ct: exclusive scan (block 0) + Ti/Tj tables (blocks 1..200) ==
__global__ __launch_bounds__(256) void k_ct(
    const int* __restrict__ counts, int* __restrict__ cursors,
    const float* __restrict__ emb,
    const float* __restrict__ Wai, const float* __restrict__ bai,
    const float* __restrict__ Waj, const float* __restrict__ baj,
    const float* __restrict__ Wgam, const float* __restrict__ Wexp,
    float* __restrict__ Ti0, float* __restrict__ Ti1,
    float* __restrict__ Tj0, float* __restrict__ Tj1)
{
    const int b = blockIdx.x, t = threadIdx.x;
    if (b == 0) {
        __shared__ int part[256];
        const int CH = (NATOMS + 255) / 256;
        int base = t * CH, s = 0;
        for (int i = 0; i < CH; i++) { int idx = base + i; if (idx < NATOMS) s += counts[idx]; }
        part[t] = s;
        __syncthreads();
        for (int d = 1; d < 256; d <<= 1) {
            int v = (t >= d) ? part[t - d] : 0;
            __syncthreads();
            part[t] += v;
            __syncthreads();
        }
        int run = (t == 0) ? 0 : part[t - 1];
        for (int i = 0; i < CH; i++) {
            int idx = base + i;
            if (idx < NATOMS) { cursors[idx] = run; run += counts[idx]; }
        }
        return;
    }
    __shared__ float ya[256], za[256];
    const int side = (b >= 101);
    const int m = side ? b - 101 : b - 1;
    const float* er = emb + m*EMBD;
    const float* W1 = side ? Waj : Wai;
    const float* b1 = side ? baj : bai;
    float s = b1[t];
    #pragma unroll 8
    for (int k = 0; k < EMBD; k++) s += er[k] * W1[k*EMBD + t];
    ya[t] = s;
    __syncthreads();
    const float* G = Wgam + (size_t)(side ? 512 : 256) * EMBD;
    s = 0.f;
    #pragma unroll 8
    for (int k = 0; k < EMBD; k++) s += ya[k] * G[k*EMBD + t];
    za[t] = s;
    __syncthreads();
    const int half = t >> 7, ff = t & 127;
    const float* WX = Wexp + (size_t)half*EMBD*FOUT;
    s = 0.f;
    #pragma unroll 8
    for (int k = 0; k < EMBD; k++) s += za[k] * WX[k*FOUT + ff];
    float* dst = side ? (half ? Tj1 : Tj0) : (half ? Ti1 : Ti0);
    dst[m*FOUT + ff] = s;
}

// ================= k_edge: transform + FULL 64B record CSR scatter ==============
// rec[p] = 16 dwords: rr[0..11] fp32 | ab bf16x2 | gg bf16x2 | xy bf16x2 | ez<<16
// zdj[p] = zd | j0<<8
__global__ __launch_bounds__(256) void k_edge(
    const int* __restrict__ z, const int* __restrict__ esrc, const int* __restrict__ edst,
    const float* __restrict__ ew, const float* __restrict__ evec, const float* __restrict__ noise,
    const float* __restrict__ Qg, const float* __restrict__ Qn, const float* __restrict__ sv,
    int* __restrict__ cursors,
    float4* __restrict__ rec, unsigned* __restrict__ zdj)
{
    __shared__ float qgL[52*12], qnL[52*12];
    __shared__ float nbuf[256*11];
    __shared__ float vbuf[768];
    const int t = threadIdx.x;
    const int e0 = blockIdx.x * 256;

    for (int i = t; i < 52*12; i += 256) { qgL[i] = Qg[i]; qnL[i] = Qn[i]; }
    #pragma unroll
    for (int q = 0; q < 10; q++) {
        int idx = q*256 + t; long long g = (long long)e0*10 + idx;
        if (g < (long long)NEDGES*10) { int r_ = idx/10; nbuf[r_*11 + (idx - r_*10)] = noise[g]; }
    }
    #pragma unroll
    for (int q = 0; q < 3; q++) {
        int idx = q*256 + t; long long g = (long long)e0*3 + idx;
        if (g < (long long)NEDGES*3) vbuf[idx] = evec[g];
    }
    __syncthreads();

    int e = e0 + t;
    if (e >= NEDGES) return;
    float w = ew[e];
    float C = (w < OUTERC) ? 0.5f*(__cosf(w*PI_OVER_OUTER) + 1.0f) : 0.0f;
    int iw = (int)(w * RBF_INVD);
    int j0 = (iw - 4) & ~3;
    j0 = max(0, min(40, j0));
    float rW[12];
    #pragma unroll
    for (int k = 0; k < 12; k++) { float tt = w - (j0+k)*RBF_D; rW[k] = exp2f(RBF_C2*tt*tt); }
    float hg[NGATE], hn[NGATE];
    #pragma unroll
    for (int g2 = 0; g2 < NGATE; g2++) { hg[g2] = 0.f; hn[g2] = 0.f; }
    #pragma unroll
    for (int k = 0; k < 12; k++) {
        float rk = rW[k];
        const float* qg = &qgL[(j0+k)*12];
        const float* qn = &qnL[(j0+k)*12];
        float4 ga = *(const float4*)qg; float4 gb = *(const float4*)(qg+4);
        float2 gc = *(const float2*)(qg+8);
        float4 na = *(const float4*)qn; float4 nb = *(const float4*)(qn+4);
        float2 nc = *(const float2*)(qn+8);
        hg[0]=fmaf(rk,ga.x,hg[0]); hg[1]=fmaf(rk,ga.y,hg[1]); hg[2]=fmaf(rk,ga.z,hg[2]); hg[3]=fmaf(rk,ga.w,hg[3]);
        hg[4]=fmaf(rk,gb.x,hg[4]); hg[5]=fmaf(rk,gb.y,hg[5]); hg[6]=fmaf(rk,gb.z,hg[6]); hg[7]=fmaf(rk,gb.w,hg[7]);
        hg[8]=fmaf(rk,gc.x,hg[8]); hg[9]=fmaf(rk,gc.y,hg[9]);
        hn[0]=fmaf(rk,na.x,hn[0]); hn[1]=fmaf(rk,na.y,hn[1]); hn[2]=fmaf(rk,na.z,hn[2]); hn[3]=fmaf(rk,na.w,hn[3]);
        hn[4]=fmaf(rk,nb.x,hn[4]); hn[5]=fmaf(rk,nb.y,hn[5]); hn[6]=fmaf(rk,nb.z,hn[6]); hn[7]=fmaf(rk,nb.w,hn[7]);
        hn[8]=fmaf(rk,nc.x,hn[8]); hn[9]=fmaf(rk,nc.y,hn[9]);
    }
    float H[NGATE];
    #pragma unroll
    for (int g2 = 0; g2 < NGATE; g2++) {
        float gv = C*(hg[g2] + sv[512+g2]) + sv[522+g2];
        float nv = C*(hn[g2] + sv[532+g2]) + sv[542+g2];
        H[g2] = gv + nbuf[t*11 + g2] * softplusf(nv);
    }
    float m1 = -INFINITY, m2 = -INFINITY;
    #pragma unroll
    for (int g2 = 0; g2 < NGATE; g2++) {
        float v = H[g2];
        if (v > m1) { m2 = m1; m1 = v; } else if (v > m2) { m2 = v; }
    }
    float den = 0.f;
    #pragma unroll
    for (int g2 = 0; g2 < NGATE; g2++) den += (H[g2] >= m2) ? __expf(H[g2] - m1) : 0.f;
    float inv = 1.0f / den;
    float g0 = inv;
    float g1 = __expf(m2 - m1) * inv;

    float ex = vbuf[t*3+0], ey = vbuf[t*3+1], ez = vbuf[t*3+2];
    float rn = rsqrtf(ex*ex + ey*ey + ez*ez);
    ex *= rn; ey *= rn; ez *= rn;
    int zd = z[edst[e]];
    int p = atomicAdd(&cursors[esrc[e]], 1);

    float4* rp = rec + (size_t)p*4;
    rp[0] = make_float4(rW[0], rW[1], rW[2],  rW[3]);
    rp[1] = make_float4(rW[4], rW[5], rW[6],  rW[7]);
    rp[2] = make_float4(rW[8], rW[9], rW[10], rW[11]);
    rp[3] = make_float4(__uint_as_float((bfr(C*g0)>>16)|bfr(C*g1)),
                        __uint_as_float((bfr(g0)>>16)|bfr(g1)),
                        __uint_as_float((bfr(ex)>>16)|bfr(ey)),
                        __uint_as_float(bfr(ez)));
    zdj[p] = (unsigned)zd | ((unsigned)j0 << 8);
}

// ================= k_main: streamed 64B records, VMEM broadcast, no LDS staging ==
#define DOT12F(J,A,B,Cc) { acc = A.x*Rc[J]; \
  acc=fmaf(A.y, Rc[(J)+1], acc); acc=fmaf(A.z, Rc[(J)+2],  acc); acc=fmaf(A.w, Rc[(J)+3],  acc); \
  acc=fmaf(B.x, Rc[(J)+4], acc); acc=fmaf(B.y, Rc[(J)+5],  acc); acc=fmaf(B.z, Rc[(J)+6],  acc); \
  acc=fmaf(B.w, Rc[(J)+7], acc); acc=fmaf(Cc.x,Rc[(J)+8],  acc); acc=fmaf(Cc.y,Rc[(J)+9],  acc); \
  acc=fmaf(Cc.z,Rc[(J)+10],acc); acc=fmaf(Cc.w,Rc[(J)+11], acc); }

#define FLUSH() { \
    accS[aCur-aBeg][pair][f] = make_float4(accA,accX,accY,accZ); \
    accA=accX=accY=accZ=0.f; aCur++; \
    if (aCur < aEnd) { nextEnd = neNxt; dtV = dV + tiNxt; \
        int an = aCur + 1; \
        if (an < aEnd) { neNxt = cursors[an]; tiNxt = TiT[z[an]*FOUT + f]; } \
    } else nextEnd = 0x7fffffff; }

#define COMPE(GI, ZJ, A, B, Cc, D, TJ) { \
    int gi = (GI); \
    while (gi == nextEnd) FLUSH() \
    int sw = (__builtin_amdgcn_readfirstlane((int)(ZJ)) >> 10) & 0xf; \
    unsigned du = __float_as_uint(D.x), gu = __float_as_uint(D.y); \
    unsigned xu = __float_as_uint(D.z), eu = __float_as_uint(D.w); \
    float aa  = pair ? BHI(du) : BLO(du); \
    float gg_ = pair ? BHI(gu) : BLO(gu); \
    float acc; \
    switch (sw) { \
      case 0: DOT12F(0,A,B,Cc)  break; case 1: DOT12F(4,A,B,Cc)  break; \
      case 2: DOT12F(8,A,B,Cc)  break; case 3: DOT12F(12,A,B,Cc) break; \
      case 4: DOT12F(16,A,B,Cc) break; case 5: DOT12F(20,A,B,Cc) break; \
      case 6: DOT12F(24,A,B,Cc) break; case 7: DOT12F(28,A,B,Cc) break; \
      case 8: DOT12F(32,A,B,Cc) break; case 9: DOT12F(36,A,B,Cc) break; \
      default: DOT12F(40,A,B,Cc) break; } \
    float part_ = fmaf(aa, acc + sV, gg_ * (dtV + (TJ))); \
    accA += part_; \
    accX = fmaf(BLO(xu), part_, accX); \
    accY = fmaf(BHI(xu), part_, accY); \
    accZ = fmaf(BHI(eu), part_, accZ); }

__global__ __launch_bounds__(256, 3) void k_main(
    const int* __restrict__ z, const int* __restrict__ cursors,
    const float4* __restrict__ rec, const unsigned* __restrict__ zdj,
    const float* __restrict__ R0, const float* __restrict__ R1,
    const float* __restrict__ Ti0, const float* __restrict__ Ti1,
    const float* __restrict__ Tj0, const float* __restrict__ Tj1,
    const float* __restrict__ sv, float* __restrict__ out)
{
    __shared__ float4 accS[APB][2][FOUT];
    const int tid = threadIdx.x, pair = tid >> 7, f = tid & 127;

    float Rc[52];
    const float* Rtab = pair ? R1 : R0;
    #pragma unroll
    for (int j = 0; j < NRBF; j++) Rc[j] = Rtab[j*FOUT + f];
    Rc[50] = 0.f; Rc[51] = 0.f;
    const float* TiT = pair ? Ti1 : Ti0;
    const float* TjT = pair ? Tj1 : Tj0;
    const float sV = sv[pair*FOUT + f];
    const float dV = sv[256 + pair*FOUT + f];

    const int aBeg = blockIdx.x * APB, aEnd = aBeg + APB;
    const int eBeg = aBeg ? cursors[aBeg-1] : 0;
    const int eEnd = cursors[aEnd-1];

    int aCur = aBeg;
    int nextEnd = cursors[aCur];
    float dtV = dV + TiT[z[aCur]*FOUT + f];
    int   neNxt = (aBeg+1 < aEnd) ? cursors[aBeg+1] : 0x7fffffff;
    float tiNxt = (aBeg+1 < aEnd) ? TiT[z[aBeg+1]*FOUT + f] : 0.f;
    float accA=0.f, accX=0.f, accY=0.f, accZ=0.f;

    // prime the pipeline (pad after NEDGES makes over-reads safe)
    unsigned czj0 = zdj[eBeg],   czj1 = zdj[eBeg+1];
    unsigned nzj0 = zdj[eBeg+2], nzj1 = zdj[eBeg+3];
    const float4* rp0 = rec + (size_t)eBeg*4;
    float4 cA0=rp0[0], cB0=rp0[1], cC0=rp0[2], cD0=rp0[3];
    float4 cA1=rp0[4], cB1=rp0[5], cC1=rp0[6], cD1=rp0[7];
    float ctj0 = TjT[(czj0 & 0xff)*FOUT + f];
    float ctj1 = TjT[(czj1 & 0xff)*FOUT + f];

    for (int i = eBeg; i < eEnd; i += 2) {
        // issue next-pair loads (records i+2, i+3; tj via zdj loaded 1 iter ago; zdj i+4,i+5)
        const float4* np = rec + (size_t)(i+2)*4;
        float4 nA0=np[0], nB0=np[1], nC0=np[2], nD0=np[3];
        float4 nA1=np[4], nB1=np[5], nC1=np[6], nD1=np[7];
        float ntj0 = TjT[(nzj0 & 0xff)*FOUT + f];
        float ntj1 = TjT[(nzj1 & 0xff)*FOUT + f];
        unsigned mzj0 = zdj[i+4], mzj1 = zdj[i+5];

        COMPE(i,   czj0, cA0, cB0, cC0, cD0, ctj0)
        if (i + 1 < eEnd) { COMPE(i+1, czj1, cA1, cB1, cC1, cD1, ctj1) }

        cA0=nA0; cB0=nB0; cC0=nC0; cD0=nD0;
        cA1=nA1; cB1=nB1; cC1=nC1; cD1=nD1;
        czj0=nzj0; czj1=nzj1; nzj0=mzj0; nzj1=mzj1;
        ctj0=ntj0; ctj1=ntj1;
    }
    while (aCur < aEnd) {
        accS[aCur-aBeg][pair][f] = make_float4(accA, accX, accY, accZ);
        accA=accX=accY=accZ=0.f; aCur++;
    }
    __syncthreads();
    if (tid < FOUT) {
        #pragma unroll
        for (int a2 = 0; a2 < APB; a2++) {
            float4 v0 = accS[a2][0][tid];
            float4 v1 = accS[a2][1][tid];
            int atom = aBeg + a2;
            out[(size_t)atom*FOUT + tid] = v0.x + v1.x;
            float* vb = out + (size_t)NATOMS*FOUT + (size_t)atom*3*FOUT;
            vb[tid]        = v0.y + v1.y;
            vb[FOUT+tid]   = v0.z + v1.z;
            vb[2*FOUT+tid] = v0.w + v1.w;
        }
    }
}

extern "C" void kernel_launch(void* const* d_in, const int* in_sizes, int n_in,
                              void* d_out, int out_size, void* d_ws, size_t ws_size,
                              hipStream_t stream)
{
    const int*   z    = (const int*)d_in[0];
    const int*   ei   = (const int*)d_in[3];
    const int*   esrc = ei;
    const int*   edst = ei + NEDGES;
    const float* ew   = (const float*)d_in[4];
    const float* evec = (const float*)d_in[5];
    const float* nz   = (const float*)d_in[6];
    const float* emb  = (const float*)d_in[7];
    const float* Wd   = (const float*)d_in[8];
    const float* bd   = (const float*)d_in[9];
    const float* Wdt  = (const float*)d_in[10];
    const float* bdt  = (const float*)d_in[11];
    const float* Wai  = (const float*)d_in[12];
    const float* bai  = (const float*)d_in[13];
    const float* Waj  = (const float*)d_in[14];
    const float* baj  = (const float*)d_in[15];
    const float* Wgam = (const float*)d_in[16];
    const float* bgam = (const float*)d_in[17];
    const float* Wg   = (const float*)d_in[18];
    const float* Wn   = (const float*)d_in[19];
    const float* Wexp = (const float*)d_in[20];
    const float* bexp = (const float*)d_in[21];
    float* out = (float*)d_out;

    char* w = (char*)d_ws;
    auto alloc = [&](size_t bytes) -> void* {
        void* p = (void*)w;
        w += (bytes + 255) & ~(size_t)255;
        return p;
    };
    int*   counts  = (int*)alloc(NATOMS * 4);
    int*   cursors = (int*)alloc(NATOMS * 4);
    float* R0  = (float*)alloc(NRBF*FOUT*4);
    float* R1  = (float*)alloc(NRBF*FOUT*4);
    float* Qg  = (float*)alloc(52*12*4);
    float* Qn  = (float*)alloc(52*12*4);
    float* Ti0 = (float*)alloc(100*FOUT*4);
    float* Ti1 = (float*)alloc(100*FOUT*4);
    float* Tj0 = (float*)alloc(100*FOUT*4);
    float* Tj1 = (float*)alloc(100*FOUT*4);
    float* sv  = (float*)alloc(552*4);
    float4*   rec = (float4*)alloc(((size_t)NEDGES + 8)*64);  // pad: prefetch over-reads <= +3
    unsigned* zdj = (unsigned*)alloc(((size_t)NEDGES + 8)*4); // pad: over-reads <= +5

    hipMemsetAsync(counts, 0, NATOMS*4, stream);

    {
        int grid = 52 + (NEDGES + 255) / 256;   // 1615
        k_ag<<<grid, 256, 0, stream>>>(Wd, Wdt, bd, bdt, bgam, Wgam, Wexp, bexp,
                                       Wg, Wn, esrc, counts, R0, R1, Qg, Qn, sv);
    }
    k_ct<<<201, 256, 0, stream>>>(counts, cursors, emb, Wai, bai, Waj, baj,
                                  Wgam, Wexp, Ti0, Ti1, Tj0, Tj1);
    {
        int grid = (NEDGES + 255) / 256;        // 1563
        k_edge<<<grid, 256, 0, stream>>>(z, esrc, edst, ew, evec, nz,
                                         Qg, Qn, sv, cursors, rec, zdj);
    }
    {
        int grid = NATOMS / APB;                // 2500
        k_main<<<grid, 256, 0, stream>>>(z, cursors, rec, zdj,
                                         R0, R1, Ti0, Ti1, Tj0, Tj1, sv, out);
    }
}